// Round 1
// baseline (3733.591 us; speedup 1.0000x reference)
//
#include <hip/hip_runtime.h>
#include <hip/hip_fp16.h>

// Problem dims
#define B_  256
#define T_  512
#define I_  64
#define H_  128
#define G_  384   // 3H
#define HC  256   // 2H

// Workspace byte offsets (total required ~168.6 MB)
#define O_OUT0 0ull                   // fp16 [B][T][2H]  = 67,108,864 B
#define O_XW1  67108864ull            // fp16 [B][T][3H]  = 100,663,296 B
#define O_WP   167772160ull           // packed half2 weights, 688,128 B
#define O_H1F  (O_WP + 688128ull)     // f32 [B][H] = 131,072 B

// packed-weight offsets in half2 elements; layout [K/2][384], row k2 holds (k=2*k2, 2*k2+1)
#define WP_WHH0F 0
#define WP_WHH0B 24576
#define WP_WHH1F 49152
#define WP_WHH1B 73728
#define WP_WIH0F 98304
#define WP_WIH0B 110592
#define WP_WIH1B 122880

__device__ __forceinline__ float sigm(float x)   { return 1.f / (1.f + __expf(-x)); }
__device__ __forceinline__ float tanh_f(float x) { return 1.f - 2.f / (1.f + __expf(2.f * x)); }

// Transpose+pack a [384][K] fp32 weight matrix into [K/2][384] half2.
__global__ void pack_wT(const float* __restrict__ W, __half2* __restrict__ dst,
                        int K, int total) {
    int i = blockIdx.x * 256 + threadIdx.x;
    if (i >= total) return;
    int c = i % G_;
    int k2 = i / G_;
    dst[i] = __halves2half2(__float2half(W[c * K + 2 * k2]),
                            __float2half(W[c * K + 2 * k2 + 1]));
}

// Layer-0 scan, fused input projection. One block = 2 batch rows, one direction.
// LDS: WihT fp16 48KB + WhhT fp16 96KB + staging (~7KB) = ~151.5KB -> 1 block/CU.
__launch_bounds__(384, 1)
__global__ void scan_l0(const float* __restrict__ x,
                        const __half2* __restrict__ wp,
                        const float* __restrict__ bih_f, const float* __restrict__ bhh_f,
                        const float* __restrict__ bih_b, const float* __restrict__ bhh_b,
                        __half* __restrict__ out0) {
    __shared__ __align__(16) __half2 s_wih[32 * G_];   // [k2][c], K=64
    __shared__ __align__(16) __half2 s_whh[64 * G_];   // [k2][c], K=128
    __shared__ __align__(16) float s_x[2 * I_];
    __shared__ __align__(16) float s_h[2 * H_];
    __shared__ __align__(16) float s_xw[2 * G_];
    __shared__ __align__(16) float s_gh[2 * G_];

    const int tid = threadIdx.x;
    const int dir = blockIdx.y;
    const int b0 = blockIdx.x * 2;
    const __half2* gwih = wp + (dir ? WP_WIH0B : WP_WIH0F);
    const __half2* gwhh = wp + (dir ? WP_WHH0B : WP_WHH0F);
    const float* bih = dir ? bih_b : bih_f;
    const float* bhh = dir ? bhh_b : bhh_f;

    for (int i = tid; i < 32 * G_; i += 384) s_wih[i] = gwih[i];
    for (int i = tid; i < 64 * G_; i += 384) s_whh[i] = gwhh[i];
    if (tid < 256) s_h[tid] = 0.f;
    const int c = tid;
    const float bih_c = bih[c];
    const float bhh_c = bhh[c];
    __syncthreads();

    for (int t = 0; t < T_; ++t) {
        const int tt = dir ? (T_ - 1 - t) : t;
        if (tid < 128) {  // stage x rows (2 x 64 floats)
            int r = tid >> 6, k = tid & 63;
            s_x[r * I_ + k] = x[((size_t)(b0 + r) * T_ + tt) * I_ + k];
        }
        __syncthreads();  // B1: h(prev) + x staged

        // xw = x @ Wih^T   (K=64)
        float xa0 = 0.f, xb0 = 0.f, xa1 = 0.f, xb1 = 0.f;
        const float4* x40 = (const float4*)(s_x);
        const float4* x41 = (const float4*)(s_x + I_);
#pragma unroll
        for (int q = 0; q < 16; q++) {
            float2 w0 = __half22float2(s_wih[(2 * q + 0) * G_ + c]);
            float2 w1 = __half22float2(s_wih[(2 * q + 1) * G_ + c]);
            float4 a0 = x40[q], a1 = x41[q];
            xa0 += a0.x * w0.x + a0.y * w0.y;  xb0 += a0.z * w1.x + a0.w * w1.y;
            xa1 += a1.x * w0.x + a1.y * w0.y;  xb1 += a1.z * w1.x + a1.w * w1.y;
        }
        // gh = h @ Whh^T   (K=128)
        float ga0 = 0.f, gb0 = 0.f, ga1 = 0.f, gb1 = 0.f;
        const float4* h40 = (const float4*)(s_h);
        const float4* h41 = (const float4*)(s_h + H_);
#pragma unroll
        for (int q = 0; q < 32; q++) {
            float2 w0 = __half22float2(s_whh[(2 * q + 0) * G_ + c]);
            float2 w1 = __half22float2(s_whh[(2 * q + 1) * G_ + c]);
            float4 a0 = h40[q], a1 = h41[q];
            ga0 += a0.x * w0.x + a0.y * w0.y;  gb0 += a0.z * w1.x + a0.w * w1.y;
            ga1 += a1.x * w0.x + a1.y * w0.y;  gb1 += a1.z * w1.x + a1.w * w1.y;
        }
        s_xw[c]      = bih_c + xa0 + xb0;
        s_xw[G_ + c] = bih_c + xa1 + xb1;
        s_gh[c]      = bhh_c + ga0 + gb0;
        s_gh[G_ + c] = bhh_c + ga1 + gb1;
        __syncthreads();  // B2: gates staged

        if (tid < 256) {
            int r = tid >> 7, j = tid & 127;
            const float* xw = s_xw + r * G_;
            const float* gh = s_gh + r * G_;
            float rg = sigm(xw[j] + gh[j]);
            float zg = sigm(xw[H_ + j] + gh[H_ + j]);
            float ng = tanh_f(xw[2 * H_ + j] + rg * gh[2 * H_ + j]);
            float hp = s_h[r * H_ + j];
            float hn = (1.f - zg) * ng + zg * hp;
            s_h[r * H_ + j] = hn;
            out0[((size_t)(b0 + r) * T_ + tt) * HC + dir * H_ + j] = __float2half(hn);
        }
    }
}

// xw1f = out0(fp16) @ Wih1f^T + bih1f, written fp16.  M=131072, K=256, N=384.
// Classic 64x64 tile, 4x4 microtile, fp32 accumulate.
__launch_bounds__(256)
__global__ void gemm_xw1(const __half* __restrict__ A,   // [M][256]
                         const float* __restrict__ Wf,   // [384][256]
                         const float* __restrict__ bias, // [384]
                         __half* __restrict__ Cout) {    // [M][384]
    __shared__ __align__(16) float As[32][68];
    __shared__ __align__(16) float Bs[32][68];
    const int tid = threadIdx.x;
    const int m0 = blockIdx.x * 64;
    const int n0 = blockIdx.y * 64;
    const int tx = tid & 15, ty = tid >> 4;
    const int la_m = tid >> 2;        // 0..63
    const int la_k = (tid & 3) * 8;   // 0,8,16,24
    float acc[4][4] = {};

    for (int k0 = 0; k0 < 256; k0 += 32) {
        {   // A tile: 64x32 halfs, 8 per thread
            const __half* src = A + (size_t)(m0 + la_m) * 256 + k0 + la_k;
            float4 raw = *(const float4*)src;
            const __half2* hh = (const __half2*)&raw;
#pragma unroll
            for (int i = 0; i < 4; i++) {
                float2 f = __half22float2(hh[i]);
                As[la_k + 2 * i][la_m] = f.x;
                As[la_k + 2 * i + 1][la_m] = f.y;
            }
            // B tile: 64x32 floats, 8 per thread
            const float* bsrc = Wf + (size_t)(n0 + la_m) * 256 + k0 + la_k;
            float4 b0v = *(const float4*)bsrc;
            float4 b1v = *(const float4*)(bsrc + 4);
            Bs[la_k + 0][la_m] = b0v.x; Bs[la_k + 1][la_m] = b0v.y;
            Bs[la_k + 2][la_m] = b0v.z; Bs[la_k + 3][la_m] = b0v.w;
            Bs[la_k + 4][la_m] = b1v.x; Bs[la_k + 5][la_m] = b1v.y;
            Bs[la_k + 6][la_m] = b1v.z; Bs[la_k + 7][la_m] = b1v.w;
        }
        __syncthreads();
#pragma unroll
        for (int k = 0; k < 32; k++) {
            float4 av = *(const float4*)&As[k][ty * 4];
            float4 bv = *(const float4*)&Bs[k][tx * 4];
            acc[0][0] += av.x * bv.x; acc[0][1] += av.x * bv.y; acc[0][2] += av.x * bv.z; acc[0][3] += av.x * bv.w;
            acc[1][0] += av.y * bv.x; acc[1][1] += av.y * bv.y; acc[1][2] += av.y * bv.z; acc[1][3] += av.y * bv.w;
            acc[2][0] += av.z * bv.x; acc[2][1] += av.z * bv.y; acc[2][2] += av.z * bv.z; acc[2][3] += av.z * bv.w;
            acc[3][0] += av.w * bv.x; acc[3][1] += av.w * bv.y; acc[3][2] += av.w * bv.z; acc[3][3] += av.w * bv.w;
        }
        __syncthreads();
    }
    float4 bia = *(const float4*)&bias[n0 + tx * 4];
#pragma unroll
    for (int i = 0; i < 4; i++) {
        __half2* dst = (__half2*)(Cout + (size_t)(m0 + ty * 4 + i) * G_ + n0 + tx * 4);
        dst[0] = __floats2half2_rn(acc[i][0] + bia.x, acc[i][1] + bia.y);
        dst[1] = __floats2half2_rn(acc[i][2] + bia.z, acc[i][3] + bia.w);
    }
}

// Layer-1 forward scan. xw precomputed (fp16, streamed). Only final h is kept.
__launch_bounds__(384, 1)
__global__ void scan_l1(const __half* __restrict__ xw1,
                        const __half2* __restrict__ wp,
                        const float* __restrict__ bhh,
                        float* __restrict__ h1f) {
    __shared__ __align__(16) __half2 s_whh[64 * G_];  // 96KB
    __shared__ __align__(16) float s_h[2 * H_];
    __shared__ __align__(16) float s_gh[2 * G_];
    const int tid = threadIdx.x;
    const int b0 = blockIdx.x * 2;
    const __half2* gwhh = wp + WP_WHH1F;
    for (int i = tid; i < 64 * G_; i += 384) s_whh[i] = gwhh[i];
    if (tid < 256) s_h[tid] = 0.f;
    const int c = tid;
    const float bhh_c = bhh[c];
    __syncthreads();

    for (int t = 0; t < T_; ++t) {
        float ga0 = 0.f, gb0 = 0.f, ga1 = 0.f, gb1 = 0.f;
        const float4* h40 = (const float4*)(s_h);
        const float4* h41 = (const float4*)(s_h + H_);
#pragma unroll
        for (int q = 0; q < 32; q++) {
            float2 w0 = __half22float2(s_whh[(2 * q + 0) * G_ + c]);
            float2 w1 = __half22float2(s_whh[(2 * q + 1) * G_ + c]);
            float4 a0 = h40[q], a1 = h41[q];
            ga0 += a0.x * w0.x + a0.y * w0.y;  gb0 += a0.z * w1.x + a0.w * w1.y;
            ga1 += a1.x * w0.x + a1.y * w0.y;  gb1 += a1.z * w1.x + a1.w * w1.y;
        }
        s_gh[c]      = bhh_c + ga0 + gb0;
        s_gh[G_ + c] = bhh_c + ga1 + gb1;
        __syncthreads();
        if (tid < 256) {
            int r = tid >> 7, j = tid & 127;
            const __half* xr = xw1 + ((size_t)(b0 + r) * T_ + t) * G_;
            float xwr = __half2float(xr[j]);
            float xwz = __half2float(xr[H_ + j]);
            float xwn = __half2float(xr[2 * H_ + j]);
            const float* gh = s_gh + r * G_;
            float rg = sigm(xwr + gh[j]);
            float zg = sigm(xwz + gh[H_ + j]);
            float ng = tanh_f(xwn + rg * gh[2 * H_ + j]);
            float hp = s_h[r * H_ + j];
            float hn = (1.f - zg) * ng + zg * hp;
            s_h[r * H_ + j] = hn;
        }
        __syncthreads();
    }
    if (tid < 256) {
        int r = tid >> 7, j = tid & 127;
        h1f[(size_t)(b0 + r) * H_ + j] = s_h[r * H_ + j];
    }
}

// Tail: layer-1 bwd single step (t=T-1, h0=0) + relu + FC. One block per batch row.
__launch_bounds__(384)
__global__ void final_k(const __half* __restrict__ out0,
                        const float* __restrict__ h1f,
                        const __half2* __restrict__ wp,
                        const float* __restrict__ bih1b, const float* __restrict__ bhh1b,
                        const float* __restrict__ fcw, const float* __restrict__ fcb,
                        float* __restrict__ out) {
    __shared__ __align__(16) float s_x1[HC];
    __shared__ __align__(16) float s_xw[G_];
    __shared__ __align__(16) float s_hc[HC];
    __shared__ float s_red[8];
    const int tid = threadIdx.x;
    const int b = blockIdx.x;
    if (tid < HC)
        s_x1[tid] = __half2float(out0[((size_t)b * T_ + (T_ - 1)) * HC + tid]);
    __syncthreads();

    {   // xw1b at t=T-1: K=256 dot with packed-T Wih1b
        const __half2* w1b = wp + WP_WIH1B;
        float acc0 = 0.f, acc1 = 0.f;
        const float2* xv = (const float2*)s_x1;
#pragma unroll 8
        for (int k2 = 0; k2 < 128; k2 += 2) {
            float2 w0 = __half22float2(w1b[k2 * G_ + tid]);
            float2 w1 = __half22float2(w1b[(k2 + 1) * G_ + tid]);
            float2 a0 = xv[k2], a1 = xv[k2 + 1];
            acc0 += a0.x * w0.x + a0.y * w0.y;
            acc1 += a1.x * w1.x + a1.y * w1.y;
        }
        s_xw[tid] = bih1b[tid] + acc0 + acc1;
    }
    __syncthreads();
    if (tid < H_) {
        int j = tid;
        float rg = sigm(s_xw[j] + bhh1b[j]);
        float zg = sigm(s_xw[H_ + j] + bhh1b[H_ + j]);
        float ng = tanh_f(s_xw[2 * H_ + j] + rg * bhh1b[2 * H_ + j]);
        float hb = (1.f - zg) * ng;                 // h0 = 0
        s_hc[H_ + j] = fmaxf(hb, 0.f);
        s_hc[j] = fmaxf(h1f[(size_t)b * H_ + j], 0.f);
    }
    __syncthreads();
    if (tid < HC) {
        float hv = s_hc[tid];
        float p0 = hv * fcw[tid];
        float p1 = hv * fcw[HC + tid];
#pragma unroll
        for (int off = 32; off; off >>= 1) {
            p0 += __shfl_down(p0, off);
            p1 += __shfl_down(p1, off);
        }
        if ((tid & 63) == 0) { s_red[(tid >> 6) * 2] = p0; s_red[(tid >> 6) * 2 + 1] = p1; }
    }
    __syncthreads();
    if (tid == 0) {
        out[b * 2 + 0] = fcb[0] + s_red[0] + s_red[2] + s_red[4] + s_red[6];
        out[b * 2 + 1] = fcb[1] + s_red[1] + s_red[3] + s_red[5] + s_red[7];
    }
}

extern "C" void kernel_launch(void* const* d_in, const int* in_sizes, int n_in,
                              void* d_out, int out_size, void* d_ws, size_t ws_size,
                              hipStream_t stream) {
    (void)in_sizes; (void)n_in; (void)out_size; (void)ws_size;
    const float* x     = (const float*)d_in[0];
    const float* Whh0f = (const float*)d_in[2];
    const float* bih0f = (const float*)d_in[3];
    const float* bhh0f = (const float*)d_in[4];
    const float* Wih0f = (const float*)d_in[1];
    const float* Wih0b = (const float*)d_in[5];
    const float* Whh0b = (const float*)d_in[6];
    const float* bih0b = (const float*)d_in[7];
    const float* bhh0b = (const float*)d_in[8];
    const float* Wih1f = (const float*)d_in[9];
    const float* Whh1f = (const float*)d_in[10];
    const float* bih1f = (const float*)d_in[11];
    const float* bhh1f = (const float*)d_in[12];
    const float* Wih1b = (const float*)d_in[13];
    const float* Whh1b = (const float*)d_in[14];
    const float* bih1b = (const float*)d_in[15];
    const float* bhh1b = (const float*)d_in[16];
    const float* fcw   = (const float*)d_in[17];
    const float* fcb   = (const float*)d_in[18];

    char* ws = (char*)d_ws;
    __half*  out0 = (__half*)(ws + O_OUT0);
    __half*  xw1  = (__half*)(ws + O_XW1);
    __half2* wp   = (__half2*)(ws + O_WP);
    float*   h1f  = (float*)(ws + O_H1F);
    float*   out  = (float*)d_out;

    // Pack/transposed fp16 weights
    pack_wT<<<96, 256, 0, stream>>>(Whh0f, wp + WP_WHH0F, 128, 24576);
    pack_wT<<<96, 256, 0, stream>>>(Whh0b, wp + WP_WHH0B, 128, 24576);
    pack_wT<<<96, 256, 0, stream>>>(Whh1f, wp + WP_WHH1F, 128, 24576);
    pack_wT<<<96, 256, 0, stream>>>(Whh1b, wp + WP_WHH1B, 128, 24576);
    pack_wT<<<48, 256, 0, stream>>>(Wih0f, wp + WP_WIH0F, 64, 12288);
    pack_wT<<<48, 256, 0, stream>>>(Wih0b, wp + WP_WIH0B, 64, 12288);
    pack_wT<<<192, 256, 0, stream>>>(Wih1b, wp + WP_WIH1B, 256, 49152);

    // Layer 0: both directions, fused input projection
    scan_l0<<<dim3(128, 2), 384, 0, stream>>>(x, wp, bih0f, bhh0f, bih0b, bhh0b, out0);

    // Layer 1 fwd input projections (big GEMM)
    gemm_xw1<<<dim3(2048, 6), 256, 0, stream>>>(out0, Wih1f, bih1f, xw1);

    // Layer 1 fwd scan (keeps only final h)
    scan_l1<<<128, 384, 0, stream>>>(xw1, wp, bhh1f, h1f);

    // Layer 1 bwd single step + relu + FC
    final_k<<<256, 384, 0, stream>>>(out0, h1f, wp, bih1b, bhh1b, fcw, fcb, out);
}

// Round 2
// 1745.378 us; speedup vs baseline: 2.1391x; 2.1391x over previous
//
#include <hip/hip_runtime.h>
#include <hip/hip_fp16.h>

#define B_  256
#define T_  512
#define I_  64
#define H_  128
#define G_  384
#define HC  256

// Workspace byte offsets (total ~168.1 MB, same budget as passing R1)
#define O_OUT0 0ull                    // fp16 [B][T][2H] = 67,108,864
#define O_XW1  67108864ull             // fp16 [B][T][3H] = 100,663,296
#define O_WP   167772160ull            // packed half2 Wih1b, 196,608
#define O_H1F  (O_WP + 196608ull)      // f32 [B][H]

typedef _Float16 h8 __attribute__((ext_vector_type(8)));
typedef float    f4 __attribute__((ext_vector_type(4)));

__device__ __forceinline__ float sigm(float x)   { return 1.f / (1.f + __expf(-x)); }
__device__ __forceinline__ float tanh_f(float x) { return 1.f - 2.f / (1.f + __expf(2.f * x)); }

__device__ __forceinline__ h8 load_w8(const float* src) {
    f4 a = *(const f4*)src;
    f4 b = *(const f4*)(src + 4);
    h8 v;
    v[0]=(_Float16)a[0]; v[1]=(_Float16)a[1]; v[2]=(_Float16)a[2]; v[3]=(_Float16)a[3];
    v[4]=(_Float16)b[0]; v[5]=(_Float16)b[1]; v[6]=(_Float16)b[2]; v[7]=(_Float16)b[3];
    return v;
}

// Transpose+pack a [384][K] fp32 weight into [K/2][384] half2 (for final_k).
__global__ void pack_wT(const float* __restrict__ W, __half2* __restrict__ dst,
                        int K, int total) {
    int i = blockIdx.x * 256 + threadIdx.x;
    if (i >= total) return;
    int c = i % G_;
    int k2 = i / G_;
    dst[i] = __halves2half2(__float2half(W[c * K + 2 * k2]),
                            __float2half(W[c * K + 2 * k2 + 1]));
}

// ---------------- Layer-0 scan: MFMA recurrent + fused x-projection ----------------
// 16 batch rows/block, 2 dirs via blockIdx.y. 512 threads = 8 waves, 48 cols each.
// Whh/Wih B-fragments register-resident (fp16). accX/accH kept separate (n-gate).
__launch_bounds__(512, 1)
__global__ void scan_l0(const float* __restrict__ x,
                        const float* __restrict__ Wih_f, const float* __restrict__ Whh_f,
                        const float* __restrict__ bih_f, const float* __restrict__ bhh_f,
                        const float* __restrict__ Wih_b, const float* __restrict__ Whh_b,
                        const float* __restrict__ bih_b, const float* __restrict__ bhh_b,
                        _Float16* __restrict__ out0) {
    __shared__ _Float16 s_hA[16][136];   // fp16 h for MFMA A (pad: 272B rows, 2-way free)
    __shared__ float    s_hF[16][128];   // fp32 master h
    __shared__ _Float16 s_x[16][80];     // fp16 x(t) (160B rows)
    __shared__ float    s_accH[16][392];
    __shared__ float    s_accX[16][392];

    const int tid  = threadIdx.x;
    const int lane = tid & 63;
    const int w    = tid >> 6;          // wave 0..7
    const int ln15 = lane & 15;
    const int lq   = lane >> 4;         // 0..3
    const int dir  = blockIdx.y;
    const int b0   = blockIdx.x * 16;

    const float* Wih = dir ? Wih_b : Wih_f;
    const float* Whh = dir ? Whh_b : Whh_f;
    const float* bih = dir ? bih_b : bih_f;
    const float* bhh = dir ? bhh_b : bhh_f;

    // Register-resident B fragments
    h8 bh[3][4], bx[3][2];
    float bihF[3], bhhF[3];
#pragma unroll
    for (int tile = 0; tile < 3; tile++) {
        int n = 48 * w + 16 * tile + ln15;
        bihF[tile] = bih[n];
        bhhF[tile] = bhh[n];
#pragma unroll
        for (int kt = 0; kt < 4; kt++) bh[tile][kt] = load_w8(Whh + (size_t)n * H_ + kt * 32 + lq * 8);
#pragma unroll
        for (int kt = 0; kt < 2; kt++) bx[tile][kt] = load_w8(Wih + (size_t)n * I_ + kt * 32 + lq * 8);
    }

    {   // zero h, stage x(t=0)
        _Float16* pa = &s_hA[0][0];
        for (int i = tid; i < 16 * 136; i += 512) pa[i] = (_Float16)0.f;
        float* pf = &s_hF[0][0];
        for (int i = tid; i < 16 * 128; i += 512) pf[i] = 0.f;
        int xr = tid >> 5, xc = (tid & 31) * 2;
        int tt0 = dir ? (T_ - 1) : 0;
        float2 xv = *(const float2*)(x + ((size_t)(b0 + xr) * T_ + tt0) * I_ + xc);
        s_x[xr][xc] = (_Float16)xv.x;
        s_x[xr][xc + 1] = (_Float16)xv.y;
    }
    __syncthreads();

    const int ej  = tid & 127;
    const int eb0 = tid >> 7;    // 0..3
    const int xr = tid >> 5, xc = (tid & 31) * 2;

    for (int t = 0; t < T_; ++t) {
        const int tt = dir ? (T_ - 1 - t) : t;
        float2 xpre;
        if (t < T_ - 1) {
            int tn = dir ? (tt - 1) : (tt + 1);
            xpre = *(const float2*)(x + ((size_t)(b0 + xr) * T_ + tn) * I_ + xc);
        }
        // acc init with biases
        f4 accH[3], accX[3];
#pragma unroll
        for (int tile = 0; tile < 3; tile++) {
            accH[tile] = (f4){bhhF[tile], bhhF[tile], bhhF[tile], bhhF[tile]};
            accX[tile] = (f4){bihF[tile], bihF[tile], bihF[tile], bihF[tile]};
        }
        // A fragments
        h8 ah[4], ax[2];
#pragma unroll
        for (int kt = 0; kt < 4; kt++) ah[kt] = *(const h8*)&s_hA[ln15][kt * 32 + lq * 8];
#pragma unroll
        for (int kt = 0; kt < 2; kt++) ax[kt] = *(const h8*)&s_x[ln15][kt * 32 + lq * 8];
        // MFMA
#pragma unroll
        for (int tile = 0; tile < 3; tile++) {
#pragma unroll
            for (int kt = 0; kt < 4; kt++)
                accH[tile] = __builtin_amdgcn_mfma_f32_16x16x32_f16(ah[kt], bh[tile][kt], accH[tile], 0, 0, 0);
#pragma unroll
            for (int kt = 0; kt < 2; kt++)
                accX[tile] = __builtin_amdgcn_mfma_f32_16x16x32_f16(ax[kt], bx[tile][kt], accX[tile], 0, 0, 0);
        }
        // write accs
#pragma unroll
        for (int tile = 0; tile < 3; tile++) {
            int col = 48 * w + 16 * tile + ln15;
#pragma unroll
            for (int reg = 0; reg < 4; reg++) {
                s_accH[lq * 4 + reg][col] = accH[tile][reg];
                s_accX[lq * 4 + reg][col] = accX[tile][reg];
            }
        }
        __syncthreads();
        // gate elementwise: 4 (b, ej) pairs per thread
#pragma unroll
        for (int i = 0; i < 4; i++) {
            int b = 4 * i + eb0;
            float gr = s_accX[b][ej] + s_accH[b][ej];
            float gz = s_accX[b][128 + ej] + s_accH[b][128 + ej];
            float gxn = s_accX[b][256 + ej];
            float ghn = s_accH[b][256 + ej];
            float r = sigm(gr);
            float z = sigm(gz);
            float n = tanh_f(gxn + r * ghn);
            float hp = s_hF[b][ej];
            float hn = n + z * (hp - n);
            s_hF[b][ej] = hn;
            s_hA[b][ej] = (_Float16)hn;
            out0[((size_t)(b0 + b) * T_ + tt) * HC + dir * H_ + ej] = (_Float16)hn;
        }
        if (t < T_ - 1) {
            s_x[xr][xc] = (_Float16)xpre.x;
            s_x[xr][xc + 1] = (_Float16)xpre.y;
        }
        __syncthreads();
    }
}

// ---------------- MFMA GEMM: xw1 = out0 @ Wih1f^T + bih1f ----------------
// M=131072, N=384, K=256. 128x128 tiles, BK=32, 256 thr (2x2 waves, 64x64 each).
__launch_bounds__(256)
__global__ void gemm_xw1(const _Float16* __restrict__ A,  // [M][256]
                         const float* __restrict__ Wf,    // [384][256]
                         const float* __restrict__ bias,
                         _Float16* __restrict__ C) {      // [M][384]
    __shared__ _Float16 sA[128][40];
    __shared__ _Float16 sB[128][40];
    const int tid  = threadIdx.x;
    const int lane = tid & 63;
    const int w    = tid >> 6;
    const int wm   = w & 1, wn = w >> 1;
    const int ln15 = lane & 15, lq = lane >> 4;
    const size_t m0 = (size_t)blockIdx.x * 128;
    const int    n0 = blockIdx.y * 128;
    const int sr = tid >> 1, sc = (tid & 1) * 16;

    f4 acc[4][4] = {};

    for (int k0 = 0; k0 < 256; k0 += 32) {
        f4 av0 = *(const f4*)(A + (m0 + sr) * 256 + k0 + sc);
        f4 av1 = *(const f4*)(A + (m0 + sr) * 256 + k0 + sc + 8);
        const float* bsrc = Wf + (size_t)(n0 + sr) * 256 + k0 + sc;
        f4 b0v = *(const f4*)bsrc;
        f4 b1v = *(const f4*)(bsrc + 4);
        f4 b2v = *(const f4*)(bsrc + 8);
        f4 b3v = *(const f4*)(bsrc + 12);
        *(f4*)&sA[sr][sc]     = av0;
        *(f4*)&sA[sr][sc + 8] = av1;
        _Float16* bd = &sB[sr][sc];
        bd[0]=(_Float16)b0v[0]; bd[1]=(_Float16)b0v[1]; bd[2]=(_Float16)b0v[2]; bd[3]=(_Float16)b0v[3];
        bd[4]=(_Float16)b1v[0]; bd[5]=(_Float16)b1v[1]; bd[6]=(_Float16)b1v[2]; bd[7]=(_Float16)b1v[3];
        bd[8]=(_Float16)b2v[0]; bd[9]=(_Float16)b2v[1]; bd[10]=(_Float16)b2v[2]; bd[11]=(_Float16)b2v[3];
        bd[12]=(_Float16)b3v[0]; bd[13]=(_Float16)b3v[1]; bd[14]=(_Float16)b3v[2]; bd[15]=(_Float16)b3v[3];
        __syncthreads();
        h8 af[4], bf[4];
#pragma unroll
        for (int mt = 0; mt < 4; mt++) af[mt] = *(const h8*)&sA[wm * 64 + mt * 16 + ln15][lq * 8];
#pragma unroll
        for (int nt = 0; nt < 4; nt++) bf[nt] = *(const h8*)&sB[wn * 64 + nt * 16 + ln15][lq * 8];
#pragma unroll
        for (int mt = 0; mt < 4; mt++)
#pragma unroll
            for (int nt = 0; nt < 4; nt++)
                acc[mt][nt] = __builtin_amdgcn_mfma_f32_16x16x32_f16(af[mt], bf[nt], acc[mt][nt], 0, 0, 0);
        __syncthreads();
    }
#pragma unroll
    for (int nt = 0; nt < 4; nt++) {
        int col = n0 + wn * 64 + nt * 16 + ln15;
        float bb = bias[col];
#pragma unroll
        for (int mt = 0; mt < 4; mt++) {
            size_t row = m0 + wm * 64 + mt * 16 + lq * 4;
#pragma unroll
            for (int reg = 0; reg < 4; reg++)
                C[(row + reg) * G_ + col] = (_Float16)(acc[mt][nt][reg] + bb);
        }
    }
}

// ---------------- Layer-1 fwd scan (MFMA recurrent, xw streamed) ----------------
__launch_bounds__(512, 1)
__global__ void scan_l1(const _Float16* __restrict__ xw1,
                        const float* __restrict__ Whh,   // Whh1f [384][128]
                        const float* __restrict__ bhh,
                        float* __restrict__ h1f) {
    __shared__ _Float16 s_hA[16][136];
    __shared__ float    s_hF[16][128];
    __shared__ float    s_accH[16][392];
    __shared__ _Float16 s_xw[16][392];

    const int tid  = threadIdx.x;
    const int lane = tid & 63;
    const int w    = tid >> 6;
    const int ln15 = lane & 15;
    const int lq   = lane >> 4;
    const int b0   = blockIdx.x * 16;

    h8 bh[3][4];
    float bhhF[3];
#pragma unroll
    for (int tile = 0; tile < 3; tile++) {
        int n = 48 * w + 16 * tile + ln15;
        bhhF[tile] = bhh[n];
#pragma unroll
        for (int kt = 0; kt < 4; kt++) bh[tile][kt] = load_w8(Whh + (size_t)n * H_ + kt * 32 + lq * 8);
    }
    {
        _Float16* pa = &s_hA[0][0];
        for (int i = tid; i < 16 * 136; i += 512) pa[i] = (_Float16)0.f;
        float* pf = &s_hF[0][0];
        for (int i = tid; i < 16 * 128; i += 512) pf[i] = 0.f;
    }
    const int xr = tid >> 5, xd = tid & 31;  // row, 12-half chunk
    {   // stage xw(t=0)
        const _Float16* src = xw1 + ((size_t)(b0 + xr) * T_ + 0) * G_ + xd * 12;
        float2 a0 = *(const float2*)src;
        float2 a1 = *(const float2*)(src + 4);
        float2 a2 = *(const float2*)(src + 8);
        _Float16* dst = &s_xw[xr][xd * 12];
        *(float2*)dst = a0; *(float2*)(dst + 4) = a1; *(float2*)(dst + 8) = a2;
    }
    __syncthreads();

    const int ej = tid & 127;
    const int eb0 = tid >> 7;

    for (int t = 0; t < T_; ++t) {
        float2 xp0, xp1, xp2;
        if (t < T_ - 1) {
            const _Float16* src = xw1 + ((size_t)(b0 + xr) * T_ + t + 1) * G_ + xd * 12;
            xp0 = *(const float2*)src;
            xp1 = *(const float2*)(src + 4);
            xp2 = *(const float2*)(src + 8);
        }
        f4 accH[3];
#pragma unroll
        for (int tile = 0; tile < 3; tile++)
            accH[tile] = (f4){bhhF[tile], bhhF[tile], bhhF[tile], bhhF[tile]};
        h8 ah[4];
#pragma unroll
        for (int kt = 0; kt < 4; kt++) ah[kt] = *(const h8*)&s_hA[ln15][kt * 32 + lq * 8];
#pragma unroll
        for (int tile = 0; tile < 3; tile++)
#pragma unroll
            for (int kt = 0; kt < 4; kt++)
                accH[tile] = __builtin_amdgcn_mfma_f32_16x16x32_f16(ah[kt], bh[tile][kt], accH[tile], 0, 0, 0);
#pragma unroll
        for (int tile = 0; tile < 3; tile++) {
            int col = 48 * w + 16 * tile + ln15;
#pragma unroll
            for (int reg = 0; reg < 4; reg++)
                s_accH[lq * 4 + reg][col] = accH[tile][reg];
        }
        __syncthreads();
#pragma unroll
        for (int i = 0; i < 4; i++) {
            int b = 4 * i + eb0;
            float xwr = (float)s_xw[b][ej];
            float xwz = (float)s_xw[b][128 + ej];
            float xwn = (float)s_xw[b][256 + ej];
            float r = sigm(xwr + s_accH[b][ej]);
            float z = sigm(xwz + s_accH[b][128 + ej]);
            float n = tanh_f(xwn + r * s_accH[b][256 + ej]);
            float hp = s_hF[b][ej];
            float hn = n + z * (hp - n);
            s_hF[b][ej] = hn;
            s_hA[b][ej] = (_Float16)hn;
        }
        if (t < T_ - 1) {
            _Float16* dst = &s_xw[xr][xd * 12];
            *(float2*)dst = xp0; *(float2*)(dst + 4) = xp1; *(float2*)(dst + 8) = xp2;
        }
        __syncthreads();
    }
#pragma unroll
    for (int i = 0; i < 4; i++) {
        int b = 4 * i + eb0;
        h1f[(size_t)(b0 + b) * H_ + ej] = s_hF[b][ej];
    }
}

// ---------------- Tail: layer-1 bwd single step + relu + FC ----------------
__launch_bounds__(384)
__global__ void final_k(const _Float16* __restrict__ out0,
                        const float* __restrict__ h1f,
                        const __half2* __restrict__ w1b,   // packed Wih1b [128][384]
                        const float* __restrict__ bih1b, const float* __restrict__ bhh1b,
                        const float* __restrict__ fcw, const float* __restrict__ fcb,
                        float* __restrict__ out) {
    __shared__ __align__(16) float s_x1[HC];
    __shared__ __align__(16) float s_xw[G_];
    __shared__ __align__(16) float s_hc[HC];
    __shared__ float s_red[8];
    const int tid = threadIdx.x;
    const int b = blockIdx.x;
    if (tid < HC)
        s_x1[tid] = (float)out0[((size_t)b * T_ + (T_ - 1)) * HC + tid];
    __syncthreads();
    {
        float acc0 = 0.f, acc1 = 0.f;
        const float2* xv = (const float2*)s_x1;
#pragma unroll 8
        for (int k2 = 0; k2 < 128; k2 += 2) {
            float2 w0 = __half22float2(w1b[k2 * G_ + tid]);
            float2 w1 = __half22float2(w1b[(k2 + 1) * G_ + tid]);
            float2 a0 = xv[k2], a1 = xv[k2 + 1];
            acc0 += a0.x * w0.x + a0.y * w0.y;
            acc1 += a1.x * w1.x + a1.y * w1.y;
        }
        s_xw[tid] = bih1b[tid] + acc0 + acc1;
    }
    __syncthreads();
    if (tid < H_) {
        int j = tid;
        float rg = sigm(s_xw[j] + bhh1b[j]);
        float zg = sigm(s_xw[H_ + j] + bhh1b[H_ + j]);
        float ng = tanh_f(s_xw[2 * H_ + j] + rg * bhh1b[2 * H_ + j]);
        float hb = (1.f - zg) * ng;
        s_hc[H_ + j] = fmaxf(hb, 0.f);
        s_hc[j] = fmaxf(h1f[(size_t)b * H_ + j], 0.f);
    }
    __syncthreads();
    if (tid < HC) {
        float hv = s_hc[tid];
        float p0 = hv * fcw[tid];
        float p1 = hv * fcw[HC + tid];
#pragma unroll
        for (int off = 32; off; off >>= 1) {
            p0 += __shfl_down(p0, off);
            p1 += __shfl_down(p1, off);
        }
        if ((tid & 63) == 0) { s_red[(tid >> 6) * 2] = p0; s_red[(tid >> 6) * 2 + 1] = p1; }
    }
    __syncthreads();
    if (tid == 0) {
        out[b * 2 + 0] = fcb[0] + s_red[0] + s_red[2] + s_red[4] + s_red[6];
        out[b * 2 + 1] = fcb[1] + s_red[1] + s_red[3] + s_red[5] + s_red[7];
    }
}

extern "C" void kernel_launch(void* const* d_in, const int* in_sizes, int n_in,
                              void* d_out, int out_size, void* d_ws, size_t ws_size,
                              hipStream_t stream) {
    (void)in_sizes; (void)n_in; (void)out_size; (void)ws_size;
    const float* x     = (const float*)d_in[0];
    const float* Wih0f = (const float*)d_in[1];
    const float* Whh0f = (const float*)d_in[2];
    const float* bih0f = (const float*)d_in[3];
    const float* bhh0f = (const float*)d_in[4];
    const float* Wih0b = (const float*)d_in[5];
    const float* Whh0b = (const float*)d_in[6];
    const float* bih0b = (const float*)d_in[7];
    const float* bhh0b = (const float*)d_in[8];
    const float* Wih1f = (const float*)d_in[9];
    const float* Whh1f = (const float*)d_in[10];
    const float* bih1f = (const float*)d_in[11];
    const float* bhh1f = (const float*)d_in[12];
    const float* Wih1b = (const float*)d_in[13];
    const float* bih1b = (const float*)d_in[15];
    const float* bhh1b = (const float*)d_in[16];
    const float* fcw   = (const float*)d_in[17];
    const float* fcb   = (const float*)d_in[18];

    char* ws = (char*)d_ws;
    _Float16* out0 = (_Float16*)(ws + O_OUT0);
    _Float16* xw1  = (_Float16*)(ws + O_XW1);
    __half2*  wp   = (__half2*)(ws + O_WP);
    float*    h1f  = (float*)(ws + O_H1F);
    float*    out  = (float*)d_out;

    pack_wT<<<192, 256, 0, stream>>>(Wih1b, wp, 256, 49152);

    scan_l0<<<dim3(16, 2), 512, 0, stream>>>(x, Wih0f, Whh0f, bih0f, bhh0f,
                                             Wih0b, Whh0b, bih0b, bhh0b, out0);

    gemm_xw1<<<dim3(1024, 3), 256, 0, stream>>>(out0, Wih1f, bih1f, xw1);

    scan_l1<<<16, 512, 0, stream>>>(xw1, Whh1f, bhh1f, h1f);

    final_k<<<256, 384, 0, stream>>>(out0, h1f, wp, bih1b, bhh1b, fcw, fcb, out);
}

// Round 3
// 1321.407 us; speedup vs baseline: 2.8255x; 1.3208x over previous
//
#include <hip/hip_runtime.h>
#include <hip/hip_fp16.h>

#define B_  256
#define T_  512
#define I_  64
#define H_  128
#define G_  384
#define HC  256

// Workspace byte offsets (total ~168.1 MB)
#define O_OUT0 0ull                    // fp16 [B][T][2H] = 67,108,864
#define O_XW1  67108864ull             // fp16 [B][T][3H] = 100,663,296
#define O_WP   167772160ull            // packed half2 Wih1b, 196,608
#define O_H1F  (O_WP + 196608ull)      // f32 [B][H]

typedef _Float16 h8 __attribute__((ext_vector_type(8)));
typedef float    f4 __attribute__((ext_vector_type(4)));

__device__ __forceinline__ float sigm(float x)   { return 1.f / (1.f + __expf(-x)); }
__device__ __forceinline__ float tanh_f(float x) { return 1.f - 2.f / (1.f + __expf(2.f * x)); }

__device__ __forceinline__ h8 load_w8(const float* src) {
    f4 a = *(const f4*)src;
    f4 b = *(const f4*)(src + 4);
    h8 v;
    v[0]=(_Float16)a[0]; v[1]=(_Float16)a[1]; v[2]=(_Float16)a[2]; v[3]=(_Float16)a[3];
    v[4]=(_Float16)b[0]; v[5]=(_Float16)b[1]; v[6]=(_Float16)b[2]; v[7]=(_Float16)b[3];
    return v;
}

// Transpose+pack a [384][K] fp32 weight into [K/2][384] half2 (for final_k).
__global__ void pack_wT(const float* __restrict__ W, __half2* __restrict__ dst,
                        int K, int total) {
    int i = blockIdx.x * 256 + threadIdx.x;
    if (i >= total) return;
    int c = i % G_;
    int k2 = i / G_;
    dst[i] = __halves2half2(__float2half(W[c * K + 2 * k2]),
                            __float2half(W[c * K + 2 * k2 + 1]));
}

// ---------------- Layer-0 scan: register-resident gates ----------------
// 16 batch rows/block, dirs via blockIdx.y. 8 waves; wave w owns hidden units
// 16w..16w+15 with tiles (r,z,n) so gate math + h-state stay in registers.
// Per step LDS: 4 b16 h-writes + 6 b128 frag reads; ONE barrier (dbuf).
__launch_bounds__(512, 1)
__global__ void scan_l0(const float* __restrict__ x,
                        const float* __restrict__ Wih_f, const float* __restrict__ Whh_f,
                        const float* __restrict__ bih_f, const float* __restrict__ bhh_f,
                        const float* __restrict__ Wih_b, const float* __restrict__ Whh_b,
                        const float* __restrict__ bih_b, const float* __restrict__ bhh_b,
                        _Float16* __restrict__ out0) {
    __shared__ _Float16 s_hA[2][16][136];   // dbuf fp16 h (A-layout), 272B rows
    __shared__ _Float16 s_x[2][16][80];     // dbuf fp16 x(t)

    const int tid  = threadIdx.x;
    const int lane = tid & 63;
    const int w    = tid >> 6;          // wave 0..7
    const int ln15 = lane & 15;
    const int lq   = lane >> 4;         // 0..3
    const int dir  = blockIdx.y;
    const int b0   = blockIdx.x * 16;
    const int col  = 16 * w + ln15;     // hidden unit owned by this lane

    const float* Wih = dir ? Wih_b : Wih_f;
    const float* Whh = dir ? Whh_b : Whh_f;
    const float* bih = dir ? bih_b : bih_f;
    const float* bhh = dir ? bhh_b : bhh_f;

    // Register-resident B fragments, gate-permuted: tile g = gate g of unit `col`
    h8 bh[3][4], bx[3][2];
    float bihF[3], bhhF[3];
#pragma unroll
    for (int g = 0; g < 3; g++) {
        int n = g * H_ + col;
        bihF[g] = bih[n];
        bhhF[g] = bhh[n];
#pragma unroll
        for (int kt = 0; kt < 4; kt++) bh[g][kt] = load_w8(Whh + (size_t)n * H_ + kt * 32 + lq * 8);
#pragma unroll
        for (int kt = 0; kt < 2; kt++) bx[g][kt] = load_w8(Wih + (size_t)n * I_ + kt * 32 + lq * 8);
    }

    const int xr = tid >> 5, xc = (tid & 31) * 2;
    {   // zero h buf0, stage x(t=0) into buf0
        _Float16* pa = &s_hA[0][0][0];
        for (int i = tid; i < 16 * 136; i += 512) pa[i] = (_Float16)0.f;
        int tt0 = dir ? (T_ - 1) : 0;
        float2 xv = *(const float2*)(x + ((size_t)(b0 + xr) * T_ + tt0) * I_ + xc);
        s_x[0][xr][xc]     = (_Float16)xv.x;
        s_x[0][xr][xc + 1] = (_Float16)xv.y;
    }
    float hF[4] = {0.f, 0.f, 0.f, 0.f};
    __syncthreads();

    for (int t = 0; t < T_; ++t) {
        const int buf = t & 1;
        const int tt = dir ? (T_ - 1 - t) : t;
        // A fragments (h + x) from current buffer
        h8 ah[4], axf[2];
#pragma unroll
        for (int kt = 0; kt < 4; kt++) ah[kt] = *(const h8*)&s_hA[buf][ln15][kt * 32 + lq * 8];
#pragma unroll
        for (int kt = 0; kt < 2; kt++) axf[kt] = *(const h8*)&s_x[buf][ln15][kt * 32 + lq * 8];
        // prefetch x(t+1)
        float2 xpre;
        if (t < T_ - 1) {
            int tn = dir ? (tt - 1) : (tt + 1);
            xpre = *(const float2*)(x + ((size_t)(b0 + xr) * T_ + tn) * I_ + xc);
        }
        f4 aH[3], aX[3];
#pragma unroll
        for (int g = 0; g < 3; g++) {
            aH[g] = (f4){bhhF[g], bhhF[g], bhhF[g], bhhF[g]};
            aX[g] = (f4){bihF[g], bihF[g], bihF[g], bihF[g]};
        }
#pragma unroll
        for (int g = 0; g < 3; g++) {
#pragma unroll
            for (int kt = 0; kt < 4; kt++)
                aH[g] = __builtin_amdgcn_mfma_f32_16x16x32_f16(ah[kt], bh[g][kt], aH[g], 0, 0, 0);
#pragma unroll
            for (int kt = 0; kt < 2; kt++)
                aX[g] = __builtin_amdgcn_mfma_f32_16x16x32_f16(axf[kt], bx[g][kt], aX[g], 0, 0, 0);
        }
        // gates fully in registers (C layout: row=lq*4+reg, col=unit)
#pragma unroll
        for (int reg = 0; reg < 4; reg++) {
            float r = sigm(aX[0][reg] + aH[0][reg]);
            float z = sigm(aX[1][reg] + aH[1][reg]);
            float n = tanh_f(aX[2][reg] + r * aH[2][reg]);
            float h = n + z * (hF[reg] - n);
            hF[reg] = h;
            int brow = lq * 4 + reg;
            out0[((size_t)(b0 + brow) * T_ + tt) * HC + dir * H_ + col] = (_Float16)h;
            s_hA[buf ^ 1][brow][col] = (_Float16)h;
        }
        if (t < T_ - 1) {
            s_x[buf ^ 1][xr][xc]     = (_Float16)xpre.x;
            s_x[buf ^ 1][xr][xc + 1] = (_Float16)xpre.y;
        }
        __syncthreads();
    }
}

// ---------------- MFMA GEMM: xw1 = out0 @ Wih1f^T + bih1f ----------------
__launch_bounds__(256)
__global__ void gemm_xw1(const _Float16* __restrict__ A,  // [M][256]
                         const float* __restrict__ Wf,    // [384][256]
                         const float* __restrict__ bias,
                         _Float16* __restrict__ C) {      // [M][384]
    __shared__ _Float16 sA[128][40];
    __shared__ _Float16 sB[128][40];
    const int tid  = threadIdx.x;
    const int lane = tid & 63;
    const int w    = tid >> 6;
    const int wm   = w & 1, wn = w >> 1;
    const int ln15 = lane & 15, lq = lane >> 4;
    const size_t m0 = (size_t)blockIdx.x * 128;
    const int    n0 = blockIdx.y * 128;
    const int sr = tid >> 1, sc = (tid & 1) * 16;

    f4 acc[4][4] = {};

    for (int k0 = 0; k0 < 256; k0 += 32) {
        f4 av0 = *(const f4*)(A + (m0 + sr) * 256 + k0 + sc);
        f4 av1 = *(const f4*)(A + (m0 + sr) * 256 + k0 + sc + 8);
        const float* bsrc = Wf + (size_t)(n0 + sr) * 256 + k0 + sc;
        f4 b0v = *(const f4*)bsrc;
        f4 b1v = *(const f4*)(bsrc + 4);
        f4 b2v = *(const f4*)(bsrc + 8);
        f4 b3v = *(const f4*)(bsrc + 12);
        *(f4*)&sA[sr][sc]     = av0;
        *(f4*)&sA[sr][sc + 8] = av1;
        _Float16* bd = &sB[sr][sc];
        bd[0]=(_Float16)b0v[0]; bd[1]=(_Float16)b0v[1]; bd[2]=(_Float16)b0v[2]; bd[3]=(_Float16)b0v[3];
        bd[4]=(_Float16)b1v[0]; bd[5]=(_Float16)b1v[1]; bd[6]=(_Float16)b1v[2]; bd[7]=(_Float16)b1v[3];
        bd[8]=(_Float16)b2v[0]; bd[9]=(_Float16)b2v[1]; bd[10]=(_Float16)b2v[2]; bd[11]=(_Float16)b2v[3];
        bd[12]=(_Float16)b3v[0]; bd[13]=(_Float16)b3v[1]; bd[14]=(_Float16)b3v[2]; bd[15]=(_Float16)b3v[3];
        __syncthreads();
        h8 af[4], bf[4];
#pragma unroll
        for (int mt = 0; mt < 4; mt++) af[mt] = *(const h8*)&sA[wm * 64 + mt * 16 + ln15][lq * 8];
#pragma unroll
        for (int nt = 0; nt < 4; nt++) bf[nt] = *(const h8*)&sB[wn * 64 + nt * 16 + ln15][lq * 8];
#pragma unroll
        for (int mt = 0; mt < 4; mt++)
#pragma unroll
            for (int nt = 0; nt < 4; nt++)
                acc[mt][nt] = __builtin_amdgcn_mfma_f32_16x16x32_f16(af[mt], bf[nt], acc[mt][nt], 0, 0, 0);
        __syncthreads();
    }
#pragma unroll
    for (int nt = 0; nt < 4; nt++) {
        int col = n0 + wn * 64 + nt * 16 + ln15;
        float bb = bias[col];
#pragma unroll
        for (int mt = 0; mt < 4; mt++) {
            size_t row = m0 + wm * 64 + mt * 16 + lq * 4;
#pragma unroll
            for (int reg = 0; reg < 4; reg++)
                C[(row + reg) * G_ + col] = (_Float16)(acc[mt][nt][reg] + bb);
        }
    }
}

// ---------------- Layer-1 fwd scan: register gates, xw streamed in C-layout ----------------
__launch_bounds__(512, 1)
__global__ void scan_l1(const _Float16* __restrict__ xw1,
                        const float* __restrict__ Whh,   // Whh1f [384][128]
                        const float* __restrict__ bhh,
                        float* __restrict__ h1f) {
    __shared__ _Float16 s_hA[2][16][136];

    const int tid  = threadIdx.x;
    const int lane = tid & 63;
    const int w    = tid >> 6;
    const int ln15 = lane & 15;
    const int lq   = lane >> 4;
    const int b0   = blockIdx.x * 16;
    const int col  = 16 * w + ln15;

    h8 bh[3][4];
    float bhhF[3];
#pragma unroll
    for (int g = 0; g < 3; g++) {
        int n = g * H_ + col;
        bhhF[g] = bhh[n];
#pragma unroll
        for (int kt = 0; kt < 4; kt++) bh[g][kt] = load_w8(Whh + (size_t)n * H_ + kt * 32 + lq * 8);
    }
    {
        _Float16* pa = &s_hA[0][0][0];
        for (int i = tid; i < 16 * 136; i += 512) pa[i] = (_Float16)0.f;
    }
    // per-reg xw base pointers (C-layout direct loads)
    const _Float16* xb[4];
#pragma unroll
    for (int reg = 0; reg < 4; reg++)
        xb[reg] = xw1 + (size_t)(b0 + lq * 4 + reg) * T_ * G_ + col;
    float xwc[3][4];
#pragma unroll
    for (int g = 0; g < 3; g++)
#pragma unroll
        for (int reg = 0; reg < 4; reg++)
            xwc[g][reg] = (float)xb[reg][g * H_];   // t = 0
    float hF[4] = {0.f, 0.f, 0.f, 0.f};
    __syncthreads();

    for (int t = 0; t < T_; ++t) {
        const int buf = t & 1;
        h8 ah[4];
#pragma unroll
        for (int kt = 0; kt < 4; kt++) ah[kt] = *(const h8*)&s_hA[buf][ln15][kt * 32 + lq * 8];
        // prefetch xw(t+1)
        float xwn[3][4];
        if (t < T_ - 1) {
#pragma unroll
            for (int g = 0; g < 3; g++)
#pragma unroll
                for (int reg = 0; reg < 4; reg++)
                    xwn[g][reg] = (float)xb[reg][(size_t)(t + 1) * G_ + g * H_];
        }
        f4 aH[3];
#pragma unroll
        for (int g = 0; g < 3; g++)
            aH[g] = (f4){bhhF[g], bhhF[g], bhhF[g], bhhF[g]};
#pragma unroll
        for (int g = 0; g < 3; g++)
#pragma unroll
            for (int kt = 0; kt < 4; kt++)
                aH[g] = __builtin_amdgcn_mfma_f32_16x16x32_f16(ah[kt], bh[g][kt], aH[g], 0, 0, 0);
#pragma unroll
        for (int reg = 0; reg < 4; reg++) {
            float r = sigm(xwc[0][reg] + aH[0][reg]);
            float z = sigm(xwc[1][reg] + aH[1][reg]);
            float n = tanh_f(xwc[2][reg] + r * aH[2][reg]);
            float h = n + z * (hF[reg] - n);
            hF[reg] = h;
            s_hA[buf ^ 1][lq * 4 + reg][col] = (_Float16)h;
        }
        if (t < T_ - 1) {
#pragma unroll
            for (int g = 0; g < 3; g++)
#pragma unroll
                for (int reg = 0; reg < 4; reg++)
                    xwc[g][reg] = xwn[g][reg];
        }
        __syncthreads();
    }
#pragma unroll
    for (int reg = 0; reg < 4; reg++)
        h1f[(size_t)(b0 + lq * 4 + reg) * H_ + col] = hF[reg];
}

// ---------------- Tail: layer-1 bwd single step + relu + FC ----------------
__launch_bounds__(384)
__global__ void final_k(const _Float16* __restrict__ out0,
                        const float* __restrict__ h1f,
                        const __half2* __restrict__ w1b,   // packed Wih1b [128][384]
                        const float* __restrict__ bih1b, const float* __restrict__ bhh1b,
                        const float* __restrict__ fcw, const float* __restrict__ fcb,
                        float* __restrict__ out) {
    __shared__ __align__(16) float s_x1[HC];
    __shared__ __align__(16) float s_xw[G_];
    __shared__ __align__(16) float s_hc[HC];
    __shared__ float s_red[8];
    const int tid = threadIdx.x;
    const int b = blockIdx.x;
    if (tid < HC)
        s_x1[tid] = (float)out0[((size_t)b * T_ + (T_ - 1)) * HC + tid];
    __syncthreads();
    {
        float acc0 = 0.f, acc1 = 0.f;
        const float2* xv = (const float2*)s_x1;
#pragma unroll 8
        for (int k2 = 0; k2 < 128; k2 += 2) {
            float2 w0 = __half22float2(w1b[k2 * G_ + tid]);
            float2 w1 = __half22float2(w1b[(k2 + 1) * G_ + tid]);
            float2 a0 = xv[k2], a1 = xv[k2 + 1];
            acc0 += a0.x * w0.x + a0.y * w0.y;
            acc1 += a1.x * w1.x + a1.y * w1.y;
        }
        s_xw[tid] = bih1b[tid] + acc0 + acc1;
    }
    __syncthreads();
    if (tid < H_) {
        int j = tid;
        float rg = sigm(s_xw[j] + bhh1b[j]);
        float zg = sigm(s_xw[H_ + j] + bhh1b[H_ + j]);
        float ng = tanh_f(s_xw[2 * H_ + j] + rg * bhh1b[2 * H_ + j]);
        float hb = (1.f - zg) * ng;
        s_hc[H_ + j] = fmaxf(hb, 0.f);
        s_hc[j] = fmaxf(h1f[(size_t)b * H_ + j], 0.f);
    }
    __syncthreads();
    if (tid < HC) {
        float hv = s_hc[tid];
        float p0 = hv * fcw[tid];
        float p1 = hv * fcw[HC + tid];
#pragma unroll
        for (int off = 32; off; off >>= 1) {
            p0 += __shfl_down(p0, off);
            p1 += __shfl_down(p1, off);
        }
        if ((tid & 63) == 0) { s_red[(tid >> 6) * 2] = p0; s_red[(tid >> 6) * 2 + 1] = p1; }
    }
    __syncthreads();
    if (tid == 0) {
        out[b * 2 + 0] = fcb[0] + s_red[0] + s_red[2] + s_red[4] + s_red[6];
        out[b * 2 + 1] = fcb[1] + s_red[1] + s_red[3] + s_red[5] + s_red[7];
    }
}

extern "C" void kernel_launch(void* const* d_in, const int* in_sizes, int n_in,
                              void* d_out, int out_size, void* d_ws, size_t ws_size,
                              hipStream_t stream) {
    (void)in_sizes; (void)n_in; (void)out_size; (void)ws_size;
    const float* x     = (const float*)d_in[0];
    const float* Wih0f = (const float*)d_in[1];
    const float* Whh0f = (const float*)d_in[2];
    const float* bih0f = (const float*)d_in[3];
    const float* bhh0f = (const float*)d_in[4];
    const float* Wih0b = (const float*)d_in[5];
    const float* Whh0b = (const float*)d_in[6];
    const float* bih0b = (const float*)d_in[7];
    const float* bhh0b = (const float*)d_in[8];
    const float* Wih1f = (const float*)d_in[9];
    const float* Whh1f = (const float*)d_in[10];
    const float* bih1f = (const float*)d_in[11];
    const float* bhh1f = (const float*)d_in[12];
    const float* Wih1b = (const float*)d_in[13];
    const float* bih1b = (const float*)d_in[15];
    const float* bhh1b = (const float*)d_in[16];
    const float* fcw   = (const float*)d_in[17];
    const float* fcb   = (const float*)d_in[18];

    char* ws = (char*)d_ws;
    _Float16* out0 = (_Float16*)(ws + O_OUT0);
    _Float16* xw1  = (_Float16*)(ws + O_XW1);
    __half2*  wp   = (__half2*)(ws + O_WP);
    float*    h1f  = (float*)(ws + O_H1F);
    float*    out  = (float*)d_out;

    pack_wT<<<192, 256, 0, stream>>>(Wih1b, wp, 256, 49152);

    scan_l0<<<dim3(16, 2), 512, 0, stream>>>(x, Wih0f, Whh0f, bih0f, bhh0f,
                                             Wih0b, Whh0b, bih0b, bhh0b, out0);

    gemm_xw1<<<dim3(1024, 3), 256, 0, stream>>>(out0, Wih1f, bih1f, xw1);

    scan_l1<<<16, 512, 0, stream>>>(xw1, Whh1f, bhh1f, h1f);

    final_k<<<256, 384, 0, stream>>>(out0, h1f, wp, bih1b, bhh1b, fcw, fcb, out);
}